// Round 9
// baseline (439.688 us; speedup 1.0000x reference)
//
#include <hip/hip_runtime.h>
#include <hip/hip_bf16.h>
#include <math.h>

#define GX 128
#define GY 128
#define GZ 16
#define CELLS (GX*GY*GZ)   // 262144
#define NCELLT (NB*CELLS)  // 524288
#define NB 2
#define NV 100000
#define NM (NB*NV)         // 200000
#define NN 8192
#define NK 8
#define NC 64
#define EPSV 1e-5f
#define TM 128             // conv row tile (32 rows per wave)
#define NTILE 196          // tiles per XCD slice (8*196*128 = 200704 >= NM)
#define NBLK (8*NTILE)     // 1568 conv blocks

typedef __attribute__((ext_vector_type(8))) short short8;    // 8 bf16
typedef __attribute__((ext_vector_type(4))) float floatx4;   // MFMA C/D

__device__ __forceinline__ float bf2f(unsigned short u) {
    unsigned int x = ((unsigned int)u) << 16;
    return __builtin_bit_cast(float, x);
}
__device__ __forceinline__ unsigned short f2bf(float f) {
    unsigned int u = __builtin_bit_cast(unsigned int, f);
    return (unsigned short)((u + 0x7fffu + ((u >> 16) & 1u)) >> 16);
}

// ---------------- init: grid_old = -1, stats = 0, featA zero-row ----------------
__global__ void k_init(int* __restrict__ grid, float* __restrict__ stats,
                       unsigned short* __restrict__ featA) {
    int i = blockIdx.x * 256 + threadIdx.x;
    if (i < NCELLT) grid[i] = -1;
    else if (i < NCELLT + 512) stats[i - NCELLT] = 0.f;
    else if (i < NCELLT + 512 + 64) featA[(size_t)NM * 64 + (i - NCELLT - 512)] = 0;
}

// ---------------- scatter voxel rows into grid_old (original ids) ----------------
__global__ void k_scatter(const int* __restrict__ coords, int* __restrict__ grid) {
    int gid = blockIdx.x * 256 + threadIdx.x;
    if (gid >= NM) return;
    int b = (gid >= NV) ? 1 : 0;
    int x = coords[gid * 3 + 0];
    int y = coords[gid * 3 + 1];
    int z = coords[gid * 3 + 2];
    grid[((b * GX + x) * GY + y) * GZ + z] = gid;
}

// ---------------- spatial sort step 1: per-block occupancy counts ----------------
__global__ void k_count(const int* __restrict__ grid, int* __restrict__ bcnt) {
    __shared__ int wt[4];
    int t = threadIdx.x;
    int occ = (grid[blockIdx.x * 256 + t] >= 0) ? 1 : 0;
    int w = t >> 6;
    unsigned long long m = __ballot(occ);
    if ((t & 63) == 0) wt[w] = __popcll(m);
    __syncthreads();
    if (t == 0) bcnt[blockIdx.x] = wt[0] + wt[1] + wt[2] + wt[3];
}

// ---------------- spatial sort step 2: scan 2048 block counts ----------------
__global__ void k_scan2048(const int* __restrict__ bcnt, int* __restrict__ boff) {
    __shared__ int s[256];
    int t = threadIdx.x;
    int v[8], sum = 0;
    #pragma unroll
    for (int j = 0; j < 8; ++j) {
        int x = bcnt[t * 8 + j];
        v[j] = sum;          // exclusive within chunk
        sum += x;
    }
    s[t] = sum;
    __syncthreads();
    for (int off = 1; off < 256; off <<= 1) {
        int x = (t >= off) ? s[t - off] : 0;
        __syncthreads();
        s[t] += x;
        __syncthreads();
    }
    int excl = s[t] - sum;
    #pragma unroll
    for (int j = 0; j < 8; ++j) boff[t * 8 + j] = excl + v[j];
}

// ---------------- spatial sort step 3: assign new ids ----------------
__global__ void k_assign(const int* __restrict__ gold, const int* __restrict__ boff,
                         int* __restrict__ gnew, int* __restrict__ perm,
                         int* __restrict__ scell) {
    __shared__ int wt[4];
    int t = threadIdx.x;
    int cell = blockIdx.x * 256 + t;
    int old = gold[cell];
    int occ = (old >= 0) ? 1 : 0;
    int w = t >> 6, lane = t & 63;
    unsigned long long m = __ballot(occ);
    int lp = __popcll(m & ((1ULL << lane) - 1ULL));
    if (lane == 63) wt[w] = lp + occ;
    __syncthreads();
    int wbase = 0;
    #pragma unroll
    for (int j = 0; j < 4; ++j) if (j < w) wbase += wt[j];
    int nid = boff[blockIdx.x] + wbase + lp;
    if (occ) {
        gnew[cell] = nid;
        perm[nid] = old;
        scell[nid] = cell;
    } else {
        gnew[cell] = -1;
    }
}

// ---------------- fallback id: sorted id of ORIGINAL row 0 (reference max(idx,0)) --
__global__ void k_fb(const int* __restrict__ vcoords, const int* __restrict__ gnew,
                     int* __restrict__ fbp) {
    if (threadIdx.x == 0 && blockIdx.x == 0) {
        int cell = (vcoords[0] * GY + vcoords[1]) * GZ + vcoords[2];  // batch 0
        fbp[0] = gnew[cell];
    }
}

// ---------------- weight prep: bf16, MFMA-fragment order ----------------
// Wt[((k*8 + ct*2 + ks)*64 + lane)*8 + j] = W[k][ci][co],
//   co = ct*16 + (lane&15), ci = ks*32 + (lane>>4)*8 + j
// -> each B-fragment read is lane-contiguous 16 B (1 KB per wave-op).
__global__ void k_wprep(const float* __restrict__ W1, const float* __restrict__ W2,
                        unsigned short* __restrict__ Wt1, unsigned short* __restrict__ Wt2) {
    int e = blockIdx.x * 256 + threadIdx.x;  // 27*8*64 = 13824 frag-lanes
    if (e >= 27 * 512) return;
    int lane = e & 63;
    int fr = (e >> 6) & 7;
    int k = e >> 9;
    int ct = fr >> 1, ks = fr & 1;
    int quad = lane >> 4, n16 = lane & 15;
    int co = ct * 16 + n16;
    #pragma unroll
    for (int j = 0; j < 8; ++j) {
        int ci = ks * 32 + quad * 8 + j;
        Wt1[(size_t)e * 8 + j] = f2bf(W1[(k << 12) + ci * 64 + co]);
        Wt2[(size_t)e * 8 + j] = f2bf(W2[(k << 12) + ci * 64 + co]);
    }
}

// ---------------- permute + fp32 -> bf16 (sorted feature build) ----------------
__global__ void k_tobf16s(const float* __restrict__ in, const int* __restrict__ perm,
                          unsigned short* __restrict__ out) {
    int i = blockIdx.x * 256 + threadIdx.x;   // over NM*8 (8 channels each)
    if (i >= NM * 8) return;
    int mrow = i >> 3, part = i & 7;
    int src = perm[mrow];
    const float4* s = (const float4*)(in + (size_t)src * 64 + part * 8);
    float4 a = s[0], b = s[1];
    ushort4 lo, hi;
    lo.x = f2bf(a.x); lo.y = f2bf(a.y); lo.z = f2bf(a.z); lo.w = f2bf(a.w);
    hi.x = f2bf(b.x); hi.y = f2bf(b.y); hi.z = f2bf(b.z); hi.w = f2bf(b.w);
    ushort4* d = (ushort4*)(out + (size_t)mrow * 64 + part * 8);
    d[0] = lo; d[1] = hi;
}

// ---------------- submanifold conv 3x3x3, C=64->64, bf16 MFMA, sorted space ----
// B weights via double-buffered LDS (8 KB staged once per BLOCK per k, shared by
// 4 waves -> 4x less B traffic on the L1/vector path).  A gathers stay
// direct-to-register (ring depth 2).  One __syncthreads per iter; barrier only
// needs lgkmcnt (no global->LDS ops), so A prefetch stays in flight across it.
__global__ __launch_bounds__(256, 4) void k_conv(
    const unsigned short* __restrict__ feats, const int* __restrict__ scell,
    const int* __restrict__ grid, const unsigned short* __restrict__ Wt,
    unsigned short* __restrict__ out, float* __restrict__ gsum, float* __restrict__ gsq)
{
    __shared__ int s_nidx[27 * TM];              // 13824 B; reused for BN reduction
    __shared__ int s_c[TM];
    __shared__ unsigned short s_bw[2][4096];     // 16384 B: double-buffered B tile

    int tid = threadIdx.x;
    // XCD swizzle: block bid -> tile (bid&7)*NTILE + bid>>3
    int bid = blockIdx.x;
    int tile = (bid & 7) * NTILE + (bid >> 3);
    int m0 = tile * TM;

    if (tid < TM) {
        int m = m0 + tid;
        s_c[tid] = (m < NM) ? scell[m] : -1;
    }
    __syncthreads();

    for (int e = tid; e < 27 * TM; e += 256) {
        int k = e >> 7;
        int r = e & (TM - 1);
        int dx = k / 9 - 1, dy = (k / 3) % 3 - 1, dz = k % 3 - 1;
        int cell = s_c[r];
        int ni = -1;
        if (cell >= 0) {
            int x = (cell >> 11) & 127, y = (cell >> 4) & 127, z = cell & 15;
            int nx = x + dx, ny = y + dy, nz = z + dz;
            if (nx >= 0 && nx < GX && ny >= 0 && ny < GY && nz >= 0 && nz < GZ)
                ni = grid[cell + dx * (GY * GZ) + dy * GZ + dz];
        }
        s_nidx[k * TM + r] = ni;
    }
    __syncthreads();

    int w = tid >> 6, lane = tid & 63;
    int quad = lane >> 4, n16 = lane & 15;
    const int* nrow = s_nidx + w * 32 + n16;
    const unsigned short* fq = feats + quad * 8;

    short8 afr[2][4];     // A ring, depth 2
    uint4 sreg[2];        // B staging registers (32 B/thread)

    auto stageLoad = [&](int k) {
        const uint4* src = (const uint4*)(Wt + (size_t)k * 4096) + tid;
        sreg[0] = src[0];
        sreg[1] = src[256];
    };
    auto stageStore = [&](int k) {   // waits vmcnt(4): A loads issued after stay in flight
        uint4* dst = (uint4*)s_bw[k & 1] + tid;
        dst[0]   = sreg[0];
        dst[256] = sreg[1];
    };
    auto issueA = [&](int k, short8* af) {
        int ni0 = nrow[k * TM];
        int ni1 = nrow[k * TM + 16];
        ni0 = (ni0 < 0) ? NM : ni0;     // zero-row fallback
        ni1 = (ni1 < 0) ? NM : ni1;
        const unsigned short* r0 = fq + (size_t)ni0 * 64;
        const unsigned short* r1 = fq + (size_t)ni1 * 64;
        af[0] = *(const short8*)(r0);
        af[1] = *(const short8*)(r0 + 32);
        af[2] = *(const short8*)(r1);
        af[3] = *(const short8*)(r1 + 32);
    };

    floatx4 acc[2][4];
    #pragma unroll
    for (int rt = 0; rt < 2; ++rt)
        #pragma unroll
        for (int ct = 0; ct < 4; ++ct)
            acc[rt][ct] = (floatx4){0.f, 0.f, 0.f, 0.f};

    // prologue: stage B(0) (oldest in FIFO), A(0) behind it
    stageLoad(0);
    issueA(0, afr[0]);
    stageStore(0);
    __syncthreads();

    #pragma unroll
    for (int k = 0; k < 27; ++k) {
        if (k + 1 < 27) {
            stageLoad(k + 1);                 // 2 contiguous dwordx4
            issueA(k + 1, afr[(k + 1) & 1]);  // 4 gather loads
        }
        __builtin_amdgcn_sched_barrier(0);    // loads stay above MFMAs

        const unsigned short* bb = s_bw[k & 1];
        #pragma unroll
        for (int ks = 0; ks < 2; ++ks) {
            short8 bfr[4];
            #pragma unroll
            for (int ct = 0; ct < 4; ++ct)
                bfr[ct] = *(const short8*)(bb + (ct * 2 + ks) * 512 + lane * 8);
            #pragma unroll
            for (int rt = 0; rt < 2; ++rt)
                #pragma unroll
                for (int ct = 0; ct < 4; ++ct)
                    acc[rt][ct] = __builtin_amdgcn_mfma_f32_16x16x32_bf16(
                        afr[k & 1][rt * 2 + ks], bfr[ct], acc[rt][ct], 0, 0, 0);
        }
        __builtin_amdgcn_sched_barrier(0);    // MFMAs stay above stage-store

        if (k + 1 < 27) stageStore(k + 1);
        __syncthreads();
    }

    // store bf16 conv output.  C/D layout: col = lane&15, row = quad*4 + reg
    #pragma unroll
    for (int rt = 0; rt < 2; ++rt) {
        int rbase = m0 + w * 32 + rt * 16 + quad * 4;
        #pragma unroll
        for (int rg = 0; rg < 4; ++rg) {
            int m = rbase + rg;
            if (m < NM) {
                #pragma unroll
                for (int ct = 0; ct < 4; ++ct)
                    out[(size_t)m * 64 + ct * 16 + n16] = f2bf(acc[rt][ct][rg]);
            }
        }
    }

    // BN stats from fp32 accumulators (pad rows gather only zero-row -> exact 0)
    float ps[4], pq[4];
    #pragma unroll
    for (int ct = 0; ct < 4; ++ct) { ps[ct] = 0.f; pq[ct] = 0.f; }
    #pragma unroll
    for (int rt = 0; rt < 2; ++rt)
        #pragma unroll
        for (int ct = 0; ct < 4; ++ct)
            #pragma unroll
            for (int rg = 0; rg < 4; ++rg) {
                float v = acc[rt][ct][rg];
                ps[ct] += v;
                pq[ct] += v * v;
            }
    #pragma unroll
    for (int ct = 0; ct < 4; ++ct) {
        ps[ct] += __shfl_xor(ps[ct], 16);
        ps[ct] += __shfl_xor(ps[ct], 32);
        pq[ct] += __shfl_xor(pq[ct], 16);
        pq[ct] += __shfl_xor(pq[ct], 32);
    }
    __syncthreads();
    float* red = (float*)s_nidx;
    if (lane < 16) {
        #pragma unroll
        for (int ct = 0; ct < 4; ++ct) {
            red[w * 64 + ct * 16 + n16]       = ps[ct];
            red[256 + w * 64 + ct * 16 + n16] = pq[ct];
        }
    }
    __syncthreads();
    if (tid < 64) {
        float ts = 0.f, tq = 0.f;
        #pragma unroll
        for (int ww = 0; ww < 4; ++ww) {
            ts += red[ww * 64 + tid];
            tq += red[256 + ww * 64 + tid];
        }
        atomicAdd(gsum + tid, ts);
        atomicAdd(gsq + tid, tq);
    }
}

// ---------------- BN coefficients ----------------
__global__ void k_bncoef(const float* __restrict__ gsum, const float* __restrict__ gsq,
                         const float* __restrict__ gamma, const float* __restrict__ beta,
                         float* __restrict__ coef) {
    int c = threadIdx.x;
    if (c >= 64) return;
    float mu = gsum[c] / (float)NM;
    float var = gsq[c] / (float)NM - mu * mu;
    float scale = gamma[c] / sqrtf(var + EPSV);
    coef[c] = scale;
    coef[64 + c] = beta[c] - mu * scale;
}

// ---------------- BN apply + ReLU (bf16 -> bf16) ----------------
__global__ void k_bnapply(const unsigned short* __restrict__ in, const float* __restrict__ coef,
                          unsigned short* __restrict__ out) {
    int i = blockIdx.x * 256 + threadIdx.x;  // over NM*8 groups of 8 bf16
    if (i >= NM * 8) return;
    int c8 = (i & 7) * 8;
    uint4 v = ((const uint4*)in)[i];
    unsigned int vv[4] = {v.x, v.y, v.z, v.w};
    unsigned int oo[4];
    #pragma unroll
    for (int j = 0; j < 4; ++j) {
        int c = c8 + j * 2;
        float lo = bf2f((unsigned short)(vv[j] & 0xffffu));
        float hi = bf2f((unsigned short)(vv[j] >> 16));
        lo = fmaxf(lo * coef[c]     + coef[64 + c],     0.f);
        hi = fmaxf(hi * coef[c + 1] + coef[64 + c + 1], 0.f);
        oo[j] = (unsigned int)f2bf(lo) | ((unsigned int)f2bf(hi) << 16);
    }
    uint4 o = {oo[0], oo[1], oo[2], oo[3]};
    ((uint4*)out)[i] = o;
}

// ---------------- keypoint sampling + fused BN2/ReLU + projection ----------------
__global__ __launch_bounds__(256) void k_sample(
    const float* __restrict__ kp, const float* __restrict__ query,
    const unsigned short* __restrict__ conv2, const float* __restrict__ coef2,
    const int* __restrict__ grid, const int* __restrict__ fbp,
    const float* __restrict__ projW, const float* __restrict__ projB,
    float* __restrict__ out_fused, float* __restrict__ out_vi)
{
    __shared__ float s_pw[64 * 65];
    __shared__ float s_mean[4][64];
    __shared__ int   s_idx[4][8];

    int tid = threadIdx.x;
    for (int e = tid; e < 4096; e += 256) {
        int co = e >> 6, c = e & 63;
        s_pw[co * 65 + c] = projW[e];
    }

    int w = tid >> 6, lane = tid & 63;
    int row = blockIdx.x * 4 + w;   // < 16384
    int b = row >> 13;              // NN = 8192
    float sc = coef2[lane];
    float sh = coef2[64 + lane];
    int fb = fbp[0];                // sorted id of original row 0
    __syncthreads();

    if (lane < 8) {
        int kk = lane;
        const float* kpp = kp + ((size_t)row * 8 + kk) * 3;
        int qx = min(max((int)(kpp[0] * 2.0f), 0), GX - 1);
        int qy = min(max((int)(kpp[1] * 2.0f), 0), GY - 1);
        int qz = min(max((int)(kpp[2] * 2.0f), 0), GZ - 1);
        s_idx[w][kk] = grid[((b * GX + qx) * GY + qy) * GZ + qz];
        float4 vi = make_float4((float)b, (float)qx, (float)qy, (float)qz);
        *(float4*)(out_vi + ((size_t)row * 8 + kk) * 4) = vi;
    }
    __syncthreads();

    float acc = 0.f;
    #pragma unroll
    for (int kk = 0; kk < 8; ++kk) {
        int gi = s_idx[w][kk];
        gi = gi < 0 ? fb : gi;
        float v = bf2f(conv2[(size_t)gi * 64 + lane]);
        acc += fmaxf(v * sc + sh, 0.f);      // fused BN2 + ReLU
    }
    float mean = acc * 0.125f + query[(size_t)row * 64 + lane];
    s_mean[w][lane] = mean;
    __syncthreads();

    float f = projB[lane];
    const float* pwr = s_pw + lane * 65;
    const float* mv = s_mean[w];
    #pragma unroll 8
    for (int c = 0; c < 64; ++c) f += mv[c] * pwr[c];
    out_fused[(size_t)row * 64 + lane] = f;
}

// ---------------- launch ----------------
extern "C" void kernel_launch(void* const* d_in, const int* in_sizes, int n_in,
                              void* d_out, int out_size, void* d_ws, size_t ws_size,
                              hipStream_t stream) {
    const float* keypoints = (const float*)d_in[0];
    const float* query     = (const float*)d_in[1];
    const float* vfeat     = (const float*)d_in[2];
    const int*   vcoords   = (const int*)d_in[3];
    const float* W1        = (const float*)d_in[4];
    const float* g1        = (const float*)d_in[5];
    const float* b1        = (const float*)d_in[6];
    const float* W2        = (const float*)d_in[7];
    const float* g2        = (const float*)d_in[8];
    const float* b2        = (const float*)d_in[9];
    const float* pW        = (const float*)d_in[10];
    const float* pb        = (const float*)d_in[11];

    char* ws = (char*)d_ws;
    int*            gold  = (int*)ws;                          // 2,097,152 B
    int*            gnew  = (int*)(ws + 2097152);              // 2,097,152 B
    float*          stats = (float*)(ws + 4194304);            // 2048 B
    int*            fbp   = (int*)(ws + 4196352);              // 256 B (own slot)
    int*            bcnt  = (int*)(ws + 4196608);              // 8192 B
    int*            boff  = (int*)(ws + 4204800);              // 8192 B
    int*            perm  = (int*)(ws + 4212992);              // 800,000 B
    int*            scell = (int*)(ws + 5012992);              // 800,000 B
    unsigned short* Wt1   = (unsigned short*)(ws + 5812992);   // 221,184 B
    unsigned short* Wt2   = (unsigned short*)(ws + 6034176);   // 221,184 B
    unsigned short* featA = (unsigned short*)(ws + 6255360);   // (NM+1)*128 B
    unsigned short* convo = (unsigned short*)(ws + 31855488);  // 25,600,000 B

    float* sum1 = stats,       *sq1 = stats + 64,  *coef1 = stats + 128;
    float* sum2 = stats + 256, *sq2 = stats + 320, *coef2 = stats + 384;

    int initN = NCELLT + 512 + 64;
    k_init<<<(initN + 255) / 256, 256, 0, stream>>>(gold, stats, featA);
    k_scatter<<<(NM + 255) / 256, 256, 0, stream>>>(vcoords, gold);

    // spatial renumbering: count -> scan -> assign -> fallback id
    k_count<<<NCELLT / 256, 256, 0, stream>>>(gold, bcnt);
    k_scan2048<<<1, 256, 0, stream>>>(bcnt, boff);
    k_assign<<<NCELLT / 256, 256, 0, stream>>>(gold, boff, gnew, perm, scell);
    k_fb<<<1, 64, 0, stream>>>(vcoords, gnew, fbp);

    k_wprep<<<(27 * 512 + 255) / 256, 256, 0, stream>>>(W1, W2, Wt1, Wt2);
    k_tobf16s<<<(NM * 8 + 255) / 256, 256, 0, stream>>>(vfeat, perm, featA);

    k_conv<<<NBLK, 256, 0, stream>>>(featA, scell, gnew, Wt1, convo, sum1, sq1);
    k_bncoef<<<1, 64, 0, stream>>>(sum1, sq1, g1, b1, coef1);
    k_bnapply<<<(NM * 8 + 255) / 256, 256, 0, stream>>>(convo, coef1, featA);

    k_conv<<<NBLK, 256, 0, stream>>>(featA, scell, gnew, Wt2, convo, sum2, sq2);
    k_bncoef<<<1, 64, 0, stream>>>(sum2, sq2, g2, b2, coef2);

    float* out_fused = (float*)d_out;
    float* out_vi = out_fused + (size_t)NB * NN * NC;  // 1,048,576 floats
    k_sample<<<(NB * NN) / 4, 256, 0, stream>>>(keypoints, query, convo, coef2, gnew, fbp,
                                                pW, pb, out_fused, out_vi);
}

// Round 10
// 342.637 us; speedup vs baseline: 1.2832x; 1.2832x over previous
//
#include <hip/hip_runtime.h>
#include <hip/hip_bf16.h>
#include <math.h>

#define GX 128
#define GY 128
#define GZ 16
#define CELLS (GX*GY*GZ)   // 262144
#define NCELLT (NB*CELLS)  // 524288
#define NB 2
#define NV 100000
#define NM (NB*NV)         // 200000
#define NN 8192
#define NK 8
#define NC 64
#define EPSV 1e-5f
#define TM 256             // conv row tile (64 rows per wave)
#define NTILE 98           // tiles per XCD slice (8*98*256 = 200704 >= NM)
#define NBLK (8*NTILE)     // 784 conv blocks
#define KPH 7              // k-offsets per LDS phase (4 phases, K padded to 28)

typedef __attribute__((ext_vector_type(8))) short short8;    // 8 bf16
typedef __attribute__((ext_vector_type(4))) float floatx4;   // MFMA C/D

__device__ __forceinline__ float bf2f(unsigned short u) {
    unsigned int x = ((unsigned int)u) << 16;
    return __builtin_bit_cast(float, x);
}
__device__ __forceinline__ unsigned short f2bf(float f) {
    unsigned int u = __builtin_bit_cast(unsigned int, f);
    return (unsigned short)((u + 0x7fffu + ((u >> 16) & 1u)) >> 16);
}

// ---------------- init: grid_old = -1, stats = 0, featA zero-row ----------------
__global__ void k_init(int* __restrict__ grid, float* __restrict__ stats,
                       unsigned short* __restrict__ featA) {
    int i = blockIdx.x * 256 + threadIdx.x;
    if (i < NCELLT) grid[i] = -1;
    else if (i < NCELLT + 512) stats[i - NCELLT] = 0.f;
    else if (i < NCELLT + 512 + 64) featA[(size_t)NM * 64 + (i - NCELLT - 512)] = 0;
}

// ---------------- scatter voxel rows into grid_old (original ids) ----------------
__global__ void k_scatter(const int* __restrict__ coords, int* __restrict__ grid) {
    int gid = blockIdx.x * 256 + threadIdx.x;
    if (gid >= NM) return;
    int b = (gid >= NV) ? 1 : 0;
    int x = coords[gid * 3 + 0];
    int y = coords[gid * 3 + 1];
    int z = coords[gid * 3 + 2];
    grid[((b * GX + x) * GY + y) * GZ + z] = gid;
}

// ---------------- spatial sort step 1: per-block occupancy counts ----------------
__global__ void k_count(const int* __restrict__ grid, int* __restrict__ bcnt) {
    __shared__ int wt[4];
    int t = threadIdx.x;
    int occ = (grid[blockIdx.x * 256 + t] >= 0) ? 1 : 0;
    int w = t >> 6;
    unsigned long long m = __ballot(occ);
    if ((t & 63) == 0) wt[w] = __popcll(m);
    __syncthreads();
    if (t == 0) bcnt[blockIdx.x] = wt[0] + wt[1] + wt[2] + wt[3];
}

// ---------------- spatial sort step 2: scan 2048 block counts ----------------
__global__ void k_scan2048(const int* __restrict__ bcnt, int* __restrict__ boff) {
    __shared__ int s[256];
    int t = threadIdx.x;
    int v[8], sum = 0;
    #pragma unroll
    for (int j = 0; j < 8; ++j) {
        int x = bcnt[t * 8 + j];
        v[j] = sum;          // exclusive within chunk
        sum += x;
    }
    s[t] = sum;
    __syncthreads();
    for (int off = 1; off < 256; off <<= 1) {
        int x = (t >= off) ? s[t - off] : 0;
        __syncthreads();
        s[t] += x;
        __syncthreads();
    }
    int excl = s[t] - sum;
    #pragma unroll
    for (int j = 0; j < 8; ++j) boff[t * 8 + j] = excl + v[j];
}

// ---------------- spatial sort step 3: assign new ids ----------------
__global__ void k_assign(const int* __restrict__ gold, const int* __restrict__ boff,
                         int* __restrict__ gnew, int* __restrict__ perm,
                         int* __restrict__ scell) {
    __shared__ int wt[4];
    int t = threadIdx.x;
    int cell = blockIdx.x * 256 + t;
    int old = gold[cell];
    int occ = (old >= 0) ? 1 : 0;
    int w = t >> 6, lane = t & 63;
    unsigned long long m = __ballot(occ);
    int lp = __popcll(m & ((1ULL << lane) - 1ULL));
    if (lane == 63) wt[w] = lp + occ;
    __syncthreads();
    int wbase = 0;
    #pragma unroll
    for (int j = 0; j < 4; ++j) if (j < w) wbase += wt[j];
    int nid = boff[blockIdx.x] + wbase + lp;
    if (occ) {
        gnew[cell] = nid;
        perm[nid] = old;
        scell[nid] = cell;
    } else {
        gnew[cell] = -1;
    }
}

// ---------------- fallback id: sorted id of ORIGINAL row 0 (reference max(idx,0)) --
__global__ void k_fb(const int* __restrict__ vcoords, const int* __restrict__ gnew,
                     int* __restrict__ fbp) {
    if (threadIdx.x == 0 && blockIdx.x == 0) {
        int cell = (vcoords[0] * GY + vcoords[1]) * GZ + vcoords[2];  // batch 0
        fbp[0] = gnew[cell];
    }
}

// ---------------- weight prep: bf16, MFMA-fragment order, K padded to 28 --------
// Wt[((k*8 + ct*2 + ks)*64 + lane)*8 + j] = W[k][ci][co],
//   co = ct*16 + (lane&15), ci = ks*32 + (lane>>4)*8 + j
// k = 27 is a zero dummy (so 4 phases of 7 fully unroll; A also reads zero-row).
__global__ void k_wprep(const float* __restrict__ W1, const float* __restrict__ W2,
                        unsigned short* __restrict__ Wt1, unsigned short* __restrict__ Wt2) {
    int e = blockIdx.x * 256 + threadIdx.x;  // 28*8*64 = 14336 frag-lanes
    if (e >= 28 * 512) return;
    int lane = e & 63;
    int fr = (e >> 6) & 7;
    int k = e >> 9;
    int ct = fr >> 1, ks = fr & 1;
    int quad = lane >> 4, n16 = lane & 15;
    int co = ct * 16 + n16;
    #pragma unroll
    for (int j = 0; j < 8; ++j) {
        int ci = ks * 32 + quad * 8 + j;
        unsigned short w1 = 0, w2 = 0;
        if (k < 27) {
            w1 = f2bf(W1[(k << 12) + ci * 64 + co]);
            w2 = f2bf(W2[(k << 12) + ci * 64 + co]);
        }
        Wt1[(size_t)e * 8 + j] = w1;
        Wt2[(size_t)e * 8 + j] = w2;
    }
}

// ---------------- permute + fp32 -> bf16 (sorted feature build) ----------------
__global__ void k_tobf16s(const float* __restrict__ in, const int* __restrict__ perm,
                          unsigned short* __restrict__ out) {
    int i = blockIdx.x * 256 + threadIdx.x;   // over NM*8 (8 channels each)
    if (i >= NM * 8) return;
    int mrow = i >> 3, part = i & 7;
    int src = perm[mrow];
    const float4* s = (const float4*)(in + (size_t)src * 64 + part * 8);
    float4 a = s[0], b = s[1];
    ushort4 lo, hi;
    lo.x = f2bf(a.x); lo.y = f2bf(a.y); lo.z = f2bf(a.z); lo.w = f2bf(a.w);
    hi.x = f2bf(b.x); hi.y = f2bf(b.y); hi.z = f2bf(b.z); hi.w = f2bf(b.w);
    ushort4* d = (ushort4*)(out + (size_t)mrow * 64 + part * 8);
    d[0] = lo; d[1] = hi;
}

// ---------------- submanifold conv 3x3x3, C=64->64, bf16 MFMA, sorted space ----
// 64 rows/wave (4x4 MFMA tiles, 64 AGPRs) + B staged in LDS once per 7-k phase
// (56 KB, shared by 4 waves x 7 iters -> B vector-path traffic ~zero).  Within a
// phase the k-loop is barrier-free: A gathers direct-to-register (ring 2,
// sched_barrier-pinned), B from ds_read_b128 on the separate LDS pipe.
__global__ __launch_bounds__(256, 2) void k_conv(
    const unsigned short* __restrict__ feats, const int* __restrict__ scell,
    const int* __restrict__ grid, const unsigned short* __restrict__ Wt,
    unsigned short* __restrict__ out, float* __restrict__ gsum, float* __restrict__ gsq)
{
    __shared__ unsigned short s_b[KPH * 4096];   // 57344 B: B tiles for one phase
    __shared__ int s_nidx[KPH * TM];             // 7168 B; reused for BN reduction
    __shared__ int s_c[TM];                      // 1024 B  -> total 65536 B

    int tid = threadIdx.x;
    // XCD swizzle: block bid -> tile (bid&7)*NTILE + bid>>3
    int bid = blockIdx.x;
    int tile = (bid & 7) * NTILE + (bid >> 3);
    int m0 = tile * TM;

    {
        int m = m0 + tid;
        s_c[tid] = (m < NM) ? scell[m] : -1;
    }

    int w = tid >> 6, lane = tid & 63;
    int quad = lane >> 4, n16 = lane & 15;
    const unsigned short* fq = feats + quad * 8;

    short8 afr[2][8];     // A ring, depth 2: [ring][rt*2+ks], rt in 0..3

    auto issueA = [&](int kk, short8* af) {
        #pragma unroll
        for (int rt = 0; rt < 4; ++rt) {
            int ni = s_nidx[kk * TM + w * 64 + rt * 16 + n16];
            ni = (ni < 0) ? NM : ni;    // zero-row fallback
            const unsigned short* r0 = fq + (size_t)ni * 64;
            af[rt * 2 + 0] = *(const short8*)(r0);
            af[rt * 2 + 1] = *(const short8*)(r0 + 32);
        }
    };

    floatx4 acc[4][4];
    #pragma unroll
    for (int rt = 0; rt < 4; ++rt)
        #pragma unroll
        for (int ct = 0; ct < 4; ++ct)
            acc[rt][ct] = (floatx4){0.f, 0.f, 0.f, 0.f};

    const uint4* wt4 = (const uint4*)Wt;

    for (int ph = 0; ph < 4; ++ph) {
        int k0 = ph * KPH;
        __syncthreads();   // previous phase fully consumed before restaging
        // stage B tiles for this phase: 7 x 8 KB contiguous
        #pragma unroll
        for (int i = 0; i < KPH * 2; ++i)
            ((uint4*)s_b)[i * 256 + tid] = wt4[(size_t)k0 * 512 + i * 256 + tid];
        // neighbor ids for this phase
        #pragma unroll
        for (int j = 0; j < KPH; ++j) {
            int e = j * 256 + tid;
            int kk = e >> 8;           // TM = 256
            int r = e & 255;
            int k = k0 + kk;
            int ni = -1;
            if (k < 27) {
                int dx = k / 9 - 1, dy = (k / 3) % 3 - 1, dz = k % 3 - 1;
                int cell = s_c[r];
                if (cell >= 0) {
                    int x = (cell >> 11) & 127, y = (cell >> 4) & 127, z = cell & 15;
                    int nx = x + dx, ny = y + dy, nz = z + dz;
                    if (nx >= 0 && nx < GX && ny >= 0 && ny < GY && nz >= 0 && nz < GZ)
                        ni = grid[cell + dx * (GY * GZ) + dy * GZ + dz];
                }
            }
            s_nidx[kk * TM + r] = ni;
        }
        __syncthreads();

        issueA(0, afr[0]);
        __builtin_amdgcn_sched_barrier(0);

        #pragma unroll
        for (int kk = 0; kk < KPH; ++kk) {
            if (kk + 1 < KPH) issueA(kk + 1, afr[(kk + 1) & 1]);
            __builtin_amdgcn_sched_barrier(0);   // A loads stay above MFMAs

            const unsigned short* bb = s_b + kk * 4096;
            short8 bfr[8];
            #pragma unroll
            for (int fr = 0; fr < 8; ++fr)
                bfr[fr] = *(const short8*)(bb + fr * 512 + lane * 8);

            const short8* ac = afr[kk & 1];
            #pragma unroll
            for (int ks = 0; ks < 2; ++ks)
                #pragma unroll
                for (int rt = 0; rt < 4; ++rt)
                    #pragma unroll
                    for (int ct = 0; ct < 4; ++ct)
                        acc[rt][ct] = __builtin_amdgcn_mfma_f32_16x16x32_bf16(
                            ac[rt * 2 + ks], bfr[ct * 2 + ks], acc[rt][ct], 0, 0, 0);
            __builtin_amdgcn_sched_barrier(0);   // MFMAs stay above next A loads
        }
    }

    // store bf16 conv output.  C/D layout: col = lane&15, row = quad*4 + reg
    #pragma unroll
    for (int rt = 0; rt < 4; ++rt) {
        int rbase = m0 + w * 64 + rt * 16 + quad * 4;
        #pragma unroll
        for (int rg = 0; rg < 4; ++rg) {
            int m = rbase + rg;
            if (m < NM) {
                #pragma unroll
                for (int ct = 0; ct < 4; ++ct)
                    out[(size_t)m * 64 + ct * 16 + n16] = f2bf(acc[rt][ct][rg]);
            }
        }
    }

    // BN stats from fp32 accumulators (pad rows gather only zero-row -> exact 0)
    float ps[4], pq[4];
    #pragma unroll
    for (int ct = 0; ct < 4; ++ct) { ps[ct] = 0.f; pq[ct] = 0.f; }
    #pragma unroll
    for (int rt = 0; rt < 4; ++rt)
        #pragma unroll
        for (int ct = 0; ct < 4; ++ct)
            #pragma unroll
            for (int rg = 0; rg < 4; ++rg) {
                float v = acc[rt][ct][rg];
                ps[ct] += v;
                pq[ct] += v * v;
            }
    #pragma unroll
    for (int ct = 0; ct < 4; ++ct) {
        ps[ct] += __shfl_xor(ps[ct], 16);
        ps[ct] += __shfl_xor(ps[ct], 32);
        pq[ct] += __shfl_xor(pq[ct], 16);
        pq[ct] += __shfl_xor(pq[ct], 32);
    }
    __syncthreads();
    float* red = (float*)s_nidx;
    if (lane < 16) {
        #pragma unroll
        for (int ct = 0; ct < 4; ++ct) {
            red[w * 64 + ct * 16 + n16]       = ps[ct];
            red[256 + w * 64 + ct * 16 + n16] = pq[ct];
        }
    }
    __syncthreads();
    if (tid < 64) {
        float ts = 0.f, tq = 0.f;
        #pragma unroll
        for (int ww = 0; ww < 4; ++ww) {
            ts += red[ww * 64 + tid];
            tq += red[256 + ww * 64 + tid];
        }
        atomicAdd(gsum + tid, ts);
        atomicAdd(gsq + tid, tq);
    }
}

// ---------------- BN coefficients ----------------
__global__ void k_bncoef(const float* __restrict__ gsum, const float* __restrict__ gsq,
                         const float* __restrict__ gamma, const float* __restrict__ beta,
                         float* __restrict__ coef) {
    int c = threadIdx.x;
    if (c >= 64) return;
    float mu = gsum[c] / (float)NM;
    float var = gsq[c] / (float)NM - mu * mu;
    float scale = gamma[c] / sqrtf(var + EPSV);
    coef[c] = scale;
    coef[64 + c] = beta[c] - mu * scale;
}

// ---------------- BN apply + ReLU (bf16 -> bf16) ----------------
__global__ void k_bnapply(const unsigned short* __restrict__ in, const float* __restrict__ coef,
                          unsigned short* __restrict__ out) {
    int i = blockIdx.x * 256 + threadIdx.x;  // over NM*8 groups of 8 bf16
    if (i >= NM * 8) return;
    int c8 = (i & 7) * 8;
    uint4 v = ((const uint4*)in)[i];
    unsigned int vv[4] = {v.x, v.y, v.z, v.w};
    unsigned int oo[4];
    #pragma unroll
    for (int j = 0; j < 4; ++j) {
        int c = c8 + j * 2;
        float lo = bf2f((unsigned short)(vv[j] & 0xffffu));
        float hi = bf2f((unsigned short)(vv[j] >> 16));
        lo = fmaxf(lo * coef[c]     + coef[64 + c],     0.f);
        hi = fmaxf(hi * coef[c + 1] + coef[64 + c + 1], 0.f);
        oo[j] = (unsigned int)f2bf(lo) | ((unsigned int)f2bf(hi) << 16);
    }
    uint4 o = {oo[0], oo[1], oo[2], oo[3]};
    ((uint4*)out)[i] = o;
}

// ---------------- keypoint sampling + fused BN2/ReLU + projection ----------------
__global__ __launch_bounds__(256) void k_sample(
    const float* __restrict__ kp, const float* __restrict__ query,
    const unsigned short* __restrict__ conv2, const float* __restrict__ coef2,
    const int* __restrict__ grid, const int* __restrict__ fbp,
    const float* __restrict__ projW, const float* __restrict__ projB,
    float* __restrict__ out_fused, float* __restrict__ out_vi)
{
    __shared__ float s_pw[64 * 65];
    __shared__ float s_mean[4][64];
    __shared__ int   s_idx[4][8];

    int tid = threadIdx.x;
    for (int e = tid; e < 4096; e += 256) {
        int co = e >> 6, c = e & 63;
        s_pw[co * 65 + c] = projW[e];
    }

    int w = tid >> 6, lane = tid & 63;
    int row = blockIdx.x * 4 + w;   // < 16384
    int b = row >> 13;              // NN = 8192
    float sc = coef2[lane];
    float sh = coef2[64 + lane];
    int fb = fbp[0];                // sorted id of original row 0
    __syncthreads();

    if (lane < 8) {
        int kk = lane;
        const float* kpp = kp + ((size_t)row * 8 + kk) * 3;
        int qx = min(max((int)(kpp[0] * 2.0f), 0), GX - 1);
        int qy = min(max((int)(kpp[1] * 2.0f), 0), GY - 1);
        int qz = min(max((int)(kpp[2] * 2.0f), 0), GZ - 1);
        s_idx[w][kk] = grid[((b * GX + qx) * GY + qy) * GZ + qz];
        float4 vi = make_float4((float)b, (float)qx, (float)qy, (float)qz);
        *(float4*)(out_vi + ((size_t)row * 8 + kk) * 4) = vi;
    }
    __syncthreads();

    float acc = 0.f;
    #pragma unroll
    for (int kk = 0; kk < 8; ++kk) {
        int gi = s_idx[w][kk];
        gi = gi < 0 ? fb : gi;
        float v = bf2f(conv2[(size_t)gi * 64 + lane]);
        acc += fmaxf(v * sc + sh, 0.f);      // fused BN2 + ReLU
    }
    float mean = acc * 0.125f + query[(size_t)row * 64 + lane];
    s_mean[w][lane] = mean;
    __syncthreads();

    float f = projB[lane];
    const float* pwr = s_pw + lane * 65;
    const float* mv = s_mean[w];
    #pragma unroll 8
    for (int c = 0; c < 64; ++c) f += mv[c] * pwr[c];
    out_fused[(size_t)row * 64 + lane] = f;
}

// ---------------- launch ----------------
extern "C" void kernel_launch(void* const* d_in, const int* in_sizes, int n_in,
                              void* d_out, int out_size, void* d_ws, size_t ws_size,
                              hipStream_t stream) {
    const float* keypoints = (const float*)d_in[0];
    const float* query     = (const float*)d_in[1];
    const float* vfeat     = (const float*)d_in[2];
    const int*   vcoords   = (const int*)d_in[3];
    const float* W1        = (const float*)d_in[4];
    const float* g1        = (const float*)d_in[5];
    const float* b1        = (const float*)d_in[6];
    const float* W2        = (const float*)d_in[7];
    const float* g2        = (const float*)d_in[8];
    const float* b2        = (const float*)d_in[9];
    const float* pW        = (const float*)d_in[10];
    const float* pb        = (const float*)d_in[11];

    char* ws = (char*)d_ws;
    int*            gold  = (int*)ws;                          // 2,097,152 B
    int*            gnew  = (int*)(ws + 2097152);              // 2,097,152 B
    float*          stats = (float*)(ws + 4194304);            // 2048 B
    int*            fbp   = (int*)(ws + 4196352);              // 256 B (own slot)
    int*            bcnt  = (int*)(ws + 4196608);              // 8192 B
    int*            boff  = (int*)(ws + 4204800);              // 8192 B
    int*            perm  = (int*)(ws + 4212992);              // 800,000 B
    int*            scell = (int*)(ws + 5012992);              // 800,000 B
    unsigned short* Wt1   = (unsigned short*)(ws + 5812992);   // 229,376 B (28 k's)
    unsigned short* Wt2   = (unsigned short*)(ws + 6042368);   // 229,376 B
    unsigned short* featA = (unsigned short*)(ws + 6271744);   // (NM+1)*128 B
    unsigned short* convo = (unsigned short*)(ws + 31871872);  // 25,600,000 B

    float* sum1 = stats,       *sq1 = stats + 64,  *coef1 = stats + 128;
    float* sum2 = stats + 256, *sq2 = stats + 320, *coef2 = stats + 384;

    int initN = NCELLT + 512 + 64;
    k_init<<<(initN + 255) / 256, 256, 0, stream>>>(gold, stats, featA);
    k_scatter<<<(NM + 255) / 256, 256, 0, stream>>>(vcoords, gold);

    // spatial renumbering: count -> scan -> assign -> fallback id
    k_count<<<NCELLT / 256, 256, 0, stream>>>(gold, bcnt);
    k_scan2048<<<1, 256, 0, stream>>>(bcnt, boff);
    k_assign<<<NCELLT / 256, 256, 0, stream>>>(gold, boff, gnew, perm, scell);
    k_fb<<<1, 64, 0, stream>>>(vcoords, gnew, fbp);

    k_wprep<<<(28 * 512 + 255) / 256, 256, 0, stream>>>(W1, W2, Wt1, Wt2);
    k_tobf16s<<<(NM * 8 + 255) / 256, 256, 0, stream>>>(vfeat, perm, featA);

    k_conv<<<NBLK, 256, 0, stream>>>(featA, scell, gnew, Wt1, convo, sum1, sq1);
    k_bncoef<<<1, 64, 0, stream>>>(sum1, sq1, g1, b1, coef1);
    k_bnapply<<<(NM * 8 + 255) / 256, 256, 0, stream>>>(convo, coef1, featA);

    k_conv<<<NBLK, 256, 0, stream>>>(featA, scell, gnew, Wt2, convo, sum2, sq2);
    k_bncoef<<<1, 64, 0, stream>>>(sum2, sq2, g2, b2, coef2);

    float* out_fused = (float*)d_out;
    float* out_vi = out_fused + (size_t)NB * NN * NC;  // 1,048,576 floats
    k_sample<<<(NB * NN) / 4, 256, 0, stream>>>(keypoints, query, convo, coef2, gnew, fbp,
                                                pW, pb, out_fused, out_vi);
}